// Round 10
// baseline (441.355 us; speedup 1.0000x reference)
//
#include <hip/hip_runtime.h>

// StockLSTM R10: two independent barrier domains per CU.
// MT=8 batch/block, 512 threads (8 waves), grid=512 -> 2 blocks/CU; each
// wave owns 2 m-tiles (8 hidden units). Batch cols 8-15 of the MFMA n-dim
// are zero-padded; after MFMA an in-wave __shfl remap gives every lane one
// VALID cell to update (per-CU VALU unchanged vs R9). Weights bf16 (hi-only),
// state h kept as bf16 hi+lo; x bf16 hi-only. One barrier/step.

#define TT   256
#define II   5
#define HH   64
#define OO   25
#define MT   8
#define NTHR 512
#define HSZ  1024       // h parity block: 64 k * 16 cols shorts
#define HF   65

typedef __attribute__((ext_vector_type(8))) short  short8;
typedef __attribute__((ext_vector_type(4))) float  floatx4;

#define MFMA(a, b, c) __builtin_amdgcn_mfma_f32_16x16x32_bf16(a, b, c, 0, 0, 0)

__device__ __forceinline__ float frcp(float x) { return __builtin_amdgcn_rcpf(x); }
__device__ __forceinline__ float fsig(float x) {
    return frcp(1.f + __builtin_amdgcn_exp2f(x * -1.44269504f));
}
__device__ __forceinline__ float ftanhf(float x) {
    return 1.f - 2.f * frcp(1.f + __builtin_amdgcn_exp2f(x * 2.88539008f));
}
__device__ __forceinline__ unsigned short bf16_rne(float f) {
    unsigned int u = __builtin_bit_cast(unsigned int, f);
    u += 0x7FFFu + ((u >> 16) & 1u);
    return (unsigned short)(u >> 16);
}
__device__ __forceinline__ float bf16_f(unsigned short h) {
    unsigned int u = ((unsigned int)h) << 16;
    return __builtin_bit_cast(float, u);
}
struct HiLo { short hi, lo; };
__device__ __forceinline__ HiLo split2(float v) {
    HiLo r;
    unsigned short h = bf16_rne(v);
    r.hi = (short)h;
    r.lo = (short)bf16_rne(v - bf16_f(h));
    return r;
}
__device__ __forceinline__ float cell_update(const floatx4& g, float& c) {
    const float gi = fsig  (g[0]);
    const float gf = fsig  (g[1]);
    const float gz = ftanhf(g[2]);
    const float go = fsig  (g[3]);
    c = gf * c + gi * gz;
    return go * ftanhf(c);
}

__global__ __attribute__((amdgpu_flat_work_group_size(NTHR, NTHR),
                          amdgpu_waves_per_eu(4, 4)))
void lstm_mfma6(const float* __restrict__ x,
                const float* __restrict__ Wih0, const float* __restrict__ Whh0,
                const float* __restrict__ bih0, const float* __restrict__ bhh0,
                const float* __restrict__ Wih1, const float* __restrict__ Whh1,
                const float* __restrict__ bih1, const float* __restrict__ bhh1,
                const float* __restrict__ Wfc,  const float* __restrict__ bfc,
                float* __restrict__ out)
{
    __shared__ __align__(16) unsigned short xhi[64 * 16 * 8];   // 16 KB, [dt][col][k]
    __shared__ __align__(16) unsigned short h1hi[2 * HSZ];      // 4 KB each
    __shared__ __align__(16) unsigned short h1lo[2 * HSZ];
    __shared__ __align__(16) unsigned short h2hi[2 * HSZ];
    __shared__ __align__(16) unsigned short h2lo[2 * HSZ];
    __shared__ __align__(16) float          h2f[MT * HF];

    const int tid  = threadIdx.x;
    const int w    = tid >> 6;        // wave 0..7
    const int lane = tid & 63;
    const int b    = lane & 15;       // MFMA n-col
    const int q    = lane >> 4;       // C row-quad / k-slice
    // remapped cell identity: lanes b<8 -> tile0, b>=8 -> tile1 (col b-8)
    const int sel  = b >> 3;
    const int b2   = b & 7;
    const int jm   = 8 * w + 4 * sel + q;          // this lane's hidden unit
    const int hw_off = ((jm >> 3) * 16 + b2) * 8 + (jm & 7);
    const int ro   = lane * 8;        // h fragment read offset (shorts)
    const int xro  = b * 8;           // x fragment col offset

    // ---------------- weights (bf16 hi-only), 2 m-tiles/wave ----------------
    short8 A1h[2][2];   // [tile][k-chunk] Whh0
    short8 A2h[2][4];   // [tile][chunk] 0,1: Wih1(h1); 2,3: Whh1(h2)
    short8 Axwh[2];     // [tile] Wih0: k<II valid, rest zero
    #pragma unroll
    for (int tau = 0; tau < 2; ++tau) {
        const int rr = lane & 15;
        const int g  = (rr & 3) * 64 + 8 * w + 4 * tau + (rr >> 2);
        #pragma unroll
        for (int c = 0; c < 2; ++c)
            #pragma unroll
            for (int jj = 0; jj < 8; ++jj)
                A1h[tau][c][jj] = (short)bf16_rne(Whh0[g * HH + c * 32 + q * 8 + jj]);
        #pragma unroll
        for (int c = 0; c < 4; ++c)
            #pragma unroll
            for (int jj = 0; jj < 8; ++jj) {
                const int k = c * 32 + q * 8 + jj;
                float wv = (k < HH) ? Wih1[g * HH + k] : Whh1[g * HH + (k - HH)];
                A2h[tau][c][jj] = (short)bf16_rne(wv);
            }
        #pragma unroll
        for (int jj = 0; jj < 8; ++jj) {
            const int k = q * 8 + jj;
            Axwh[tau][jj] = (k < II) ? (short)bf16_rne(Wih0[g * II + k]) : (short)0;
        }
    }
    // biases for THIS lane's remapped cell (loop-invariant)
    float b1v[4], b2v[4];
    #pragma unroll
    for (int r = 0; r < 4; ++r) {
        const int g = r * 64 + jm;
        b1v[r] = bih0[g] + bhh0[g];
        b2v[r] = bih1[g] + bhh1[g];
    }

    // ---------------- zero LDS ----------------
    for (int i = tid; i < 64 * 16 * 8 / 2; i += NTHR) ((unsigned int*)xhi)[i] = 0u;
    for (int i = tid; i < HSZ; i += NTHR) {
        ((unsigned int*)h1hi)[i] = 0u;
        ((unsigned int*)h1lo)[i] = 0u;
        ((unsigned int*)h2hi)[i] = 0u;
        ((unsigned int*)h2lo)[i] = 0u;
    }
    __syncthreads();   // zero-init must complete before refill overwrites

    const int blockBase = blockIdx.x * MT;
    auto refill_x = [&](int t0) {
        const int rb = tid >> 6, dt = tid & 63;    // 8 rows x 64 steps = 512 thr
        const float* src = x + ((size_t)(blockBase + rb) * TT + t0 + dt) * II;
        unsigned short* ph = xhi + (dt * 16 + rb) * 8;
        #pragma unroll
        for (int ii = 0; ii < II; ++ii) ph[ii] = bf16_rne(src[ii]);
    };

    float c1 = 0.f, c2 = 0.f;
    refill_x(0);
    __syncthreads();

    // ================= prologue: L1(0) =================
    {
        short8 Bxh = *(const short8*)(xhi + xro);   // dt = 0
        floatx4 z = {0.f, 0.f, 0.f, 0.f};
        floatx4 s0 = MFMA(Axwh[0], Bxh, z);
        floatx4 s1 = MFMA(Axwh[1], Bxh, z);
        floatx4 g;
        #pragma unroll
        for (int r = 0; r < 4; ++r) {
            float t1 = __shfl(s1[r], (lane - 8) & 63);
            g[r] = (sel ? t1 : s0[r]) + b1v[r];
        }
        const float h = cell_update(g, c1);
        HiLo s = split2(h);
        h1hi[hw_off] = (unsigned short)s.hi;   // parity 0
        h1lo[hw_off] = (unsigned short)s.lo;
    }
    __syncthreads();

    // ================= merged main loop: L2(i) + L1(i+1) =================
    for (int i = 0; i < TT - 1; ++i) {
        if (((i + 1) & 63) == 0) {
            refill_x(i + 1);
            __syncthreads();
        }
        const int wp = i & 1, rp = wp ^ 1;
        const int dt = (i + 1) & 63;

        short8 H1h0 = *(const short8*)(h1hi + wp * HSZ + ro);
        short8 H1l0 = *(const short8*)(h1lo + wp * HSZ + ro);
        short8 H1h1 = *(const short8*)(h1hi + wp * HSZ + 512 + ro);
        short8 H1l1 = *(const short8*)(h1lo + wp * HSZ + 512 + ro);
        short8 H2h0 = *(const short8*)(h2hi + rp * HSZ + ro);
        short8 H2l0 = *(const short8*)(h2lo + rp * HSZ + ro);
        short8 H2h1 = *(const short8*)(h2hi + rp * HSZ + 512 + ro);
        short8 H2l1 = *(const short8*)(h2lo + rp * HSZ + 512 + ro);
        short8 Bxh  = *(const short8*)(xhi + dt * 128 + xro);

        floatx4 z = {0.f, 0.f, 0.f, 0.f};
        floatx4 s2[2], s1v[2];
        #pragma unroll
        for (int tau = 0; tau < 2; ++tau) {
            floatx4 a = MFMA(A2h[tau][0], H1h0, z);
            a = MFMA(A2h[tau][0], H1l0, a);
            a = MFMA(A2h[tau][1], H1h1, a);
            a = MFMA(A2h[tau][1], H1l1, a);
            a = MFMA(A2h[tau][2], H2h0, a);
            a = MFMA(A2h[tau][2], H2l0, a);
            a = MFMA(A2h[tau][3], H2h1, a);
            a = MFMA(A2h[tau][3], H2l1, a);
            s2[tau] = a;
            floatx4 c = MFMA(Axwh[tau], Bxh, z);
            c = MFMA(A1h[tau][0], H1h0, c);
            c = MFMA(A1h[tau][0], H1l0, c);
            c = MFMA(A1h[tau][1], H1h1, c);
            c = MFMA(A1h[tau][1], H1l1, c);
            s1v[tau] = c;
        }

        // ---- remap + cell updates (one valid cell per lane per layer) ----
        floatx4 g2, g1;
        #pragma unroll
        for (int r = 0; r < 4; ++r) {
            float t2 = __shfl(s2[1][r], (lane - 8) & 63);
            g2[r] = (sel ? t2 : s2[0][r]) + b2v[r];
            float t1 = __shfl(s1v[1][r], (lane - 8) & 63);
            g1[r] = (sel ? t1 : s1v[0][r]) + b1v[r];
        }
        {
            const float h = cell_update(g2, c2);     // h2(i) -> parity wp
            HiLo s = split2(h);
            h2hi[wp * HSZ + hw_off] = (unsigned short)s.hi;
            h2lo[wp * HSZ + hw_off] = (unsigned short)s.lo;
        }
        {
            const float h = cell_update(g1, c1);     // h1(i+1) -> parity rp
            HiLo s = split2(h);
            h1hi[rp * HSZ + hw_off] = (unsigned short)s.hi;
            h1lo[rp * HSZ + hw_off] = (unsigned short)s.lo;
        }
        __syncthreads();
    }

    // ================= epilogue: L2(255) =================
    {
        const int wp = 1, rp = 0;
        short8 H1h0 = *(const short8*)(h1hi + wp * HSZ + ro);
        short8 H1l0 = *(const short8*)(h1lo + wp * HSZ + ro);
        short8 H1h1 = *(const short8*)(h1hi + wp * HSZ + 512 + ro);
        short8 H1l1 = *(const short8*)(h1lo + wp * HSZ + 512 + ro);
        short8 H2h0 = *(const short8*)(h2hi + rp * HSZ + ro);
        short8 H2l0 = *(const short8*)(h2lo + rp * HSZ + ro);
        short8 H2h1 = *(const short8*)(h2hi + rp * HSZ + 512 + ro);
        short8 H2l1 = *(const short8*)(h2lo + rp * HSZ + 512 + ro);
        floatx4 z = {0.f, 0.f, 0.f, 0.f};
        floatx4 s2[2];
        #pragma unroll
        for (int tau = 0; tau < 2; ++tau) {
            floatx4 a = MFMA(A2h[tau][0], H1h0, z);
            a = MFMA(A2h[tau][0], H1l0, a);
            a = MFMA(A2h[tau][1], H1h1, a);
            a = MFMA(A2h[tau][1], H1l1, a);
            a = MFMA(A2h[tau][2], H2h0, a);
            a = MFMA(A2h[tau][2], H2l0, a);
            a = MFMA(A2h[tau][3], H2h1, a);
            a = MFMA(A2h[tau][3], H2l1, a);
            s2[tau] = a;
        }
        floatx4 g2;
        #pragma unroll
        for (int r = 0; r < 4; ++r) {
            float t2 = __shfl(s2[1][r], (lane - 8) & 63);
            g2[r] = (sel ? t2 : s2[0][r]) + b2v[r];
        }
        const float h = cell_update(g2, c2);
        h2f[b2 * HF + jm] = h;
    }
    __syncthreads();

    // ================= FC epilogue =================
    if (tid < MT * OO) {
        const int bb = tid / OO, o = tid - bb * OO;
        float acc = bfc[o];
        const float* wr = Wfc + o * HH;
        const float* hr = h2f + bb * HF;
        #pragma unroll
        for (int j = 0; j < HH; ++j) acc += wr[j] * hr[j];
        out[((size_t)blockIdx.x * MT + bb) * OO + o] = acc;
    }
}

extern "C" void kernel_launch(void* const* d_in, const int* in_sizes, int n_in,
                              void* d_out, int out_size, void* d_ws, size_t ws_size,
                              hipStream_t stream) {
    const float* x    = (const float*)d_in[0];
    const float* Wih0 = (const float*)d_in[1];
    const float* Whh0 = (const float*)d_in[2];
    const float* bih0 = (const float*)d_in[3];
    const float* bhh0 = (const float*)d_in[4];
    const float* Wih1 = (const float*)d_in[5];
    const float* Whh1 = (const float*)d_in[6];
    const float* bih1 = (const float*)d_in[7];
    const float* bhh1 = (const float*)d_in[8];
    const float* Wfc  = (const float*)d_in[9];
    const float* bfc  = (const float*)d_in[10];
    float* out = (float*)d_out;

    dim3 grid(4096 / MT), block(NTHR);
    lstm_mfma6<<<grid, block, 0, stream>>>(x, Wih0, Whh0, bih0, bhh0,
                                           Wih1, Whh1, bih1, bhh1,
                                           Wfc, bfc, out);
}

// Round 11
// 334.723 us; speedup vs baseline: 1.3186x; 1.3186x over previous
//
#include <hip/hip_runtime.h>

// StockLSTM R11 = R9 structure (proven 334us, 56 VGPR, no spills) with
// precision terms trimmed to cut the dominant LDS-read component:
//   - x: bf16 hi only (error ~2e-4, only 5 input terms)
//   - h2: bf16 hi only (feeds only L2; ~1.6e-4/step injection)
//   - h1: keep hi+lo (deep recurrence path, feeds BOTH layers)
// => 7 ds_read_b128/step (was 10), 11 MFMA (was 14), 3 LDS writes (was 4).
// R10 lesson: do NOT grow the invariant register set (spill cliff at ~56+).

#define TT   256
#define II   5
#define HH   64
#define OO   25
#define MT   16
#define NTHR 1024
#define XP   520        // x chunk row stride (ushorts): 64*8 + 8 skew
#define HSZ  1024       // h parity block: 64 k * 16 batch shorts
#define HF   65

typedef __attribute__((ext_vector_type(8))) short  short8;
typedef __attribute__((ext_vector_type(4))) float  floatx4;

#define MFMA(a, b, c) __builtin_amdgcn_mfma_f32_16x16x32_bf16(a, b, c, 0, 0, 0)

__device__ __forceinline__ float frcp(float x) { return __builtin_amdgcn_rcpf(x); }
__device__ __forceinline__ float fsig(float x) {
    return frcp(1.f + __builtin_amdgcn_exp2f(x * -1.44269504f));
}
__device__ __forceinline__ float ftanhf(float x) {
    return 1.f - 2.f * frcp(1.f + __builtin_amdgcn_exp2f(x * 2.88539008f));
}
__device__ __forceinline__ unsigned short bf16_rne(float f) {
    unsigned int u = __builtin_bit_cast(unsigned int, f);
    u += 0x7FFFu + ((u >> 16) & 1u);
    return (unsigned short)(u >> 16);
}
__device__ __forceinline__ float bf16_f(unsigned short h) {
    unsigned int u = ((unsigned int)h) << 16;
    return __builtin_bit_cast(float, u);
}
struct HiLo { short hi, lo; };
__device__ __forceinline__ HiLo split2(float v) {
    HiLo r;
    unsigned short h = bf16_rne(v);
    r.hi = (short)h;
    r.lo = (short)bf16_rne(v - bf16_f(h));
    return r;
}
__device__ __forceinline__ float cell_update(const floatx4& aA, const floatx4& aB, float& c) {
    const float gi = fsig  (aA[0] + aB[0]);
    const float gf = fsig  (aA[1] + aB[1]);
    const float gz = ftanhf(aA[2] + aB[2]);
    const float go = fsig  (aA[3] + aB[3]);
    c = gf * c + gi * gz;
    return go * ftanhf(c);
}

__global__ __attribute__((amdgpu_flat_work_group_size(1024, 1024),
                          amdgpu_waves_per_eu(4, 4)))
void lstm_mfma7(const float* __restrict__ x,
                const float* __restrict__ Wih0, const float* __restrict__ Whh0,
                const float* __restrict__ bih0, const float* __restrict__ bhh0,
                const float* __restrict__ Wih1, const float* __restrict__ Whh1,
                const float* __restrict__ bih1, const float* __restrict__ bhh1,
                const float* __restrict__ Wfc,  const float* __restrict__ bfc,
                float* __restrict__ out)
{
    __shared__ __align__(16) unsigned short xhi[MT * XP];     // 16.6 KB
    __shared__ __align__(16) unsigned short h1hi[2 * HSZ];    // 4 KB each
    __shared__ __align__(16) unsigned short h1lo[2 * HSZ];
    __shared__ __align__(16) unsigned short h2hi[2 * HSZ];
    __shared__ __align__(16) float          h2f[MT * HF];

    const int tid   = threadIdx.x;
    const int w     = tid >> 6;
    const int lane  = tid & 63;
    const int b     = lane & 15;      // batch col
    const int q     = lane >> 4;      // k-slice / C row-quad
    const int jmine = 4 * w + q;
    const int hw_off = ((jmine >> 3) * 16 + b) * 8 + (jmine & 7);
    const int ro     = lane * 8;      // fragment read offset: lane*16B

    // ---------------- A-fragment (weight) preload — hi only ----------------
    short8 A1h[2];   // Whh0 k-chunks
    short8 A2h[4];   // 0,1: Wih1 (h1 side); 2,3: Whh1 (h2 side)
    short8 Axwh;     // Wih0: k<II valid, rest exact zero
    {
        const int rr = lane & 15;
        const int g  = (rr & 3) * 64 + 4 * w + (rr >> 2);
        #pragma unroll
        for (int c = 0; c < 2; ++c)
            #pragma unroll
            for (int jj = 0; jj < 8; ++jj)
                A1h[c][jj] = (short)bf16_rne(Whh0[g * HH + c * 32 + q * 8 + jj]);
        #pragma unroll
        for (int c = 0; c < 4; ++c)
            #pragma unroll
            for (int jj = 0; jj < 8; ++jj) {
                const int k = c * 32 + q * 8 + jj;
                float wv = (k < HH) ? Wih1[g * HH + k] : Whh1[g * HH + (k - HH)];
                A2h[c][jj] = (short)bf16_rne(wv);
            }
        #pragma unroll
        for (int jj = 0; jj < 8; ++jj) {
            const int k = q * 8 + jj;
            Axwh[jj] = (k < II) ? (short)bf16_rne(Wih0[g * II + k]) : (short)0;
        }
    }
    float bias1[4], bias2[4];
    #pragma unroll
    for (int r = 0; r < 4; ++r) {
        const int g = r * 64 + jmine;
        bias1[r] = bih0[g] + bhh0[g];
        bias2[r] = bih1[g] + bhh1[g];
    }

    // ---------------- zero LDS ----------------
    for (int i = tid; i < MT * XP / 2; i += NTHR)
        ((unsigned int*)xhi)[i] = 0u;
    for (int i = tid; i < HSZ; i += NTHR) {
        ((unsigned int*)h1hi)[i] = 0u;
        ((unsigned int*)h1lo)[i] = 0u;
        ((unsigned int*)h2hi)[i] = 0u;
    }
    float c1 = 0.f, c2 = 0.f;
    __syncthreads();

    const int blockBase = blockIdx.x * MT;

    auto refill_x = [&](int t0) {
        const int rb = tid >> 6, dt = tid & 63;
        const float* src = x + ((size_t)(blockBase + rb) * TT + t0 + dt) * II;
        unsigned short* ph = xhi + rb * XP + dt * 8;
        #pragma unroll
        for (int ii = 0; ii < II; ++ii)
            ph[ii] = bf16_rne(src[ii]);
    };

    // ================= prologue: L1(0) =================
    refill_x(0);
    __syncthreads();
    {
        short8 Bxh = *(const short8*)(xhi + b * XP);
        floatx4 aA = {bias1[0], bias1[1], bias1[2], bias1[3]};
        aA = MFMA(Axwh, Bxh, aA);
        floatx4 zero = {0.f, 0.f, 0.f, 0.f};
        const float h = cell_update(aA, zero, c1);
        HiLo s = split2(h);
        h1hi[0 * HSZ + hw_off] = (unsigned short)s.hi;
        h1lo[0 * HSZ + hw_off] = (unsigned short)s.lo;
    }
    __syncthreads();

    // ================= merged main loop: L2(i) + L1(i+1) =================
    for (int i = 0; i < TT - 1; ++i) {
        if (((i + 1) & 63) == 0) {
            refill_x(i + 1);
            __syncthreads();
        }
        const int wp = i & 1, rp = wp ^ 1;
        const int dt = (i + 1) & 63;

        short8 H1h0 = *(const short8*)(h1hi + wp * HSZ + ro);
        short8 H1l0 = *(const short8*)(h1lo + wp * HSZ + ro);
        short8 H1h1 = *(const short8*)(h1hi + wp * HSZ + 512 + ro);
        short8 H1l1 = *(const short8*)(h1lo + wp * HSZ + 512 + ro);
        short8 H2h0 = *(const short8*)(h2hi + rp * HSZ + ro);
        short8 H2h1 = *(const short8*)(h2hi + rp * HSZ + 512 + ro);
        short8 Bxh  = *(const short8*)(xhi + b * XP + dt * 8);

        // ---- L2(i): gates from [h1(i); h2(i-1)] ----
        floatx4 a2A = {bias2[0], bias2[1], bias2[2], bias2[3]};
        floatx4 a2B = {0.f, 0.f, 0.f, 0.f};
        a2A = MFMA(A2h[0], H1h0, a2A);
        a2A = MFMA(A2h[0], H1l0, a2A);
        a2A = MFMA(A2h[1], H1h1, a2A);
        a2A = MFMA(A2h[1], H1l1, a2A);
        a2B = MFMA(A2h[2], H2h0, a2B);
        a2B = MFMA(A2h[3], H2h1, a2B);

        // ---- L1(i+1): gates from [x(i+1); h1(i)] ----
        floatx4 a1A = {bias1[0], bias1[1], bias1[2], bias1[3]};
        floatx4 a1B = {0.f, 0.f, 0.f, 0.f};
        a1A = MFMA(Axwh, Bxh, a1A);
        a1B = MFMA(A1h[0], H1h0, a1B);
        a1B = MFMA(A1h[0], H1l0, a1B);
        a1A = MFMA(A1h[1], H1h1, a1A);
        a1A = MFMA(A1h[1], H1l1, a1A);

        // ---- cell updates ----
        {
            const float h = cell_update(a2A, a2B, c2);   // h2(i) -> parity wp
            h2hi[wp * HSZ + hw_off] = bf16_rne(h);
        }
        {
            const float h = cell_update(a1A, a1B, c1);   // h1(i+1) -> parity rp
            HiLo s = split2(h);
            h1hi[rp * HSZ + hw_off] = (unsigned short)s.hi;
            h1lo[rp * HSZ + hw_off] = (unsigned short)s.lo;
        }
        __syncthreads();
    }

    // ================= epilogue: L2(255) =================
    {
        const int wp = 1, rp = 0;
        short8 H1h0 = *(const short8*)(h1hi + wp * HSZ + ro);
        short8 H1l0 = *(const short8*)(h1lo + wp * HSZ + ro);
        short8 H1h1 = *(const short8*)(h1hi + wp * HSZ + 512 + ro);
        short8 H1l1 = *(const short8*)(h1lo + wp * HSZ + 512 + ro);
        short8 H2h0 = *(const short8*)(h2hi + rp * HSZ + ro);
        short8 H2h1 = *(const short8*)(h2hi + rp * HSZ + 512 + ro);
        floatx4 a2A = {bias2[0], bias2[1], bias2[2], bias2[3]};
        floatx4 a2B = {0.f, 0.f, 0.f, 0.f};
        a2A = MFMA(A2h[0], H1h0, a2A);
        a2A = MFMA(A2h[0], H1l0, a2A);
        a2A = MFMA(A2h[1], H1h1, a2A);
        a2A = MFMA(A2h[1], H1l1, a2A);
        a2B = MFMA(A2h[2], H2h0, a2B);
        a2B = MFMA(A2h[3], H2h1, a2B);
        const float h = cell_update(a2A, a2B, c2);
        h2f[b * HF + jmine] = h;
    }
    __syncthreads();

    // ================= FC epilogue =================
    if (tid < MT * OO) {
        const int bb = tid / OO, o = tid - bb * OO;
        float acc = bfc[o];
        const float* wr = Wfc + o * HH;
        const float* hr = h2f + bb * HF;
        #pragma unroll
        for (int j = 0; j < HH; ++j) acc += wr[j] * hr[j];
        out[((size_t)blockIdx.x * MT + bb) * OO + o] = acc;
    }
}

extern "C" void kernel_launch(void* const* d_in, const int* in_sizes, int n_in,
                              void* d_out, int out_size, void* d_ws, size_t ws_size,
                              hipStream_t stream) {
    const float* x    = (const float*)d_in[0];
    const float* Wih0 = (const float*)d_in[1];
    const float* Whh0 = (const float*)d_in[2];
    const float* bih0 = (const float*)d_in[3];
    const float* bhh0 = (const float*)d_in[4];
    const float* Wih1 = (const float*)d_in[5];
    const float* Whh1 = (const float*)d_in[6];
    const float* bih1 = (const float*)d_in[7];
    const float* bhh1 = (const float*)d_in[8];
    const float* Wfc  = (const float*)d_in[9];
    const float* bfc  = (const float*)d_in[10];
    float* out = (float*)d_out;

    dim3 grid(4096 / MT), block(NTHR);
    lstm_mfma7<<<grid, block, 0, stream>>>(x, Wih0, Whh0, bih0, bhh0,
                                           Wih1, Whh1, bih1, bhh1,
                                           Wfc, bfc, out);
}

// Round 12
// 283.067 us; speedup vs baseline: 1.5592x; 1.1825x over previous
//
#include <hip/hip_runtime.h>

// StockLSTM R12 = R11 with h1-lo dropped (all-bf16 state) + merged MFMA chains.
// R11 model: wall = LDS-pipe (16 waves x 7 redundant ds_read_b128 = 1344cyc)
// + VALU (1330cyc) in series. This round: reads 7->5, MFMA 11->7 (one
// dependent chain per layer, bias in C-init), h1 write = single rne.
// 64-VGPR allocator wall (R10) forbids multi-tile waves; stay 1 tile/wave.

#define TT   256
#define II   5
#define HH   64
#define OO   25
#define MT   16
#define NTHR 1024
#define XP   520        // x chunk row stride (ushorts): 64*8 + 8 skew
#define HSZ  1024       // h parity block: 64 k * 16 batch shorts
#define HF   65

typedef __attribute__((ext_vector_type(8))) short  short8;
typedef __attribute__((ext_vector_type(4))) float  floatx4;

#define MFMA(a, b, c) __builtin_amdgcn_mfma_f32_16x16x32_bf16(a, b, c, 0, 0, 0)

__device__ __forceinline__ float frcp(float x) { return __builtin_amdgcn_rcpf(x); }
__device__ __forceinline__ float fsig(float x) {
    return frcp(1.f + __builtin_amdgcn_exp2f(x * -1.44269504f));
}
__device__ __forceinline__ float ftanhf(float x) {
    return 1.f - 2.f * frcp(1.f + __builtin_amdgcn_exp2f(x * 2.88539008f));
}
__device__ __forceinline__ unsigned short bf16_rne(float f) {
    unsigned int u = __builtin_bit_cast(unsigned int, f);
    u += 0x7FFFu + ((u >> 16) & 1u);
    return (unsigned short)(u >> 16);
}
__device__ __forceinline__ float cell_update(const floatx4& g, float& c) {
    const float gi = fsig  (g[0]);
    const float gf = fsig  (g[1]);
    const float gz = ftanhf(g[2]);
    const float go = fsig  (g[3]);
    c = gf * c + gi * gz;
    return go * ftanhf(c);
}

__global__ __attribute__((amdgpu_flat_work_group_size(1024, 1024),
                          amdgpu_waves_per_eu(4, 4)))
void lstm_mfma8(const float* __restrict__ x,
                const float* __restrict__ Wih0, const float* __restrict__ Whh0,
                const float* __restrict__ bih0, const float* __restrict__ bhh0,
                const float* __restrict__ Wih1, const float* __restrict__ Whh1,
                const float* __restrict__ bih1, const float* __restrict__ bhh1,
                const float* __restrict__ Wfc,  const float* __restrict__ bfc,
                float* __restrict__ out)
{
    __shared__ __align__(16) unsigned short xhi[MT * XP];     // 16.6 KB
    __shared__ __align__(16) unsigned short h1hi[2 * HSZ];    // 4 KB each
    __shared__ __align__(16) unsigned short h2hi[2 * HSZ];
    __shared__ __align__(16) float          h2f[MT * HF];

    const int tid   = threadIdx.x;
    const int w     = tid >> 6;
    const int lane  = tid & 63;
    const int b     = lane & 15;      // batch col
    const int q     = lane >> 4;      // k-slice / C row-quad
    const int jmine = 4 * w + q;
    const int hw_off = ((jmine >> 3) * 16 + b) * 8 + (jmine & 7);
    const int ro     = lane * 8;      // fragment read offset: lane*16B

    // ---------------- A-fragment (weight) preload — bf16 hi only ----------------
    short8 A1h[2];   // Whh0 k-chunks
    short8 A2h[4];   // 0,1: Wih1 (h1 side); 2,3: Whh1 (h2 side)
    short8 Axwh;     // Wih0: k<II valid, rest exact zero
    {
        const int rr = lane & 15;
        const int g  = (rr & 3) * 64 + 4 * w + (rr >> 2);
        #pragma unroll
        for (int c = 0; c < 2; ++c)
            #pragma unroll
            for (int jj = 0; jj < 8; ++jj)
                A1h[c][jj] = (short)bf16_rne(Whh0[g * HH + c * 32 + q * 8 + jj]);
        #pragma unroll
        for (int c = 0; c < 4; ++c)
            #pragma unroll
            for (int jj = 0; jj < 8; ++jj) {
                const int k = c * 32 + q * 8 + jj;
                float wv = (k < HH) ? Wih1[g * HH + k] : Whh1[g * HH + (k - HH)];
                A2h[c][jj] = (short)bf16_rne(wv);
            }
        #pragma unroll
        for (int jj = 0; jj < 8; ++jj) {
            const int k = q * 8 + jj;
            Axwh[jj] = (k < II) ? (short)bf16_rne(Wih0[g * II + k]) : (short)0;
        }
    }
    float bias1[4], bias2[4];
    #pragma unroll
    for (int r = 0; r < 4; ++r) {
        const int g = r * 64 + jmine;
        bias1[r] = bih0[g] + bhh0[g];
        bias2[r] = bih1[g] + bhh1[g];
    }

    // ---------------- zero LDS ----------------
    for (int i = tid; i < MT * XP / 2; i += NTHR)
        ((unsigned int*)xhi)[i] = 0u;
    for (int i = tid; i < HSZ; i += NTHR) {
        ((unsigned int*)h1hi)[i] = 0u;
        ((unsigned int*)h2hi)[i] = 0u;
    }
    float c1 = 0.f, c2 = 0.f;
    __syncthreads();

    const int blockBase = blockIdx.x * MT;

    auto refill_x = [&](int t0) {
        const int rb = tid >> 6, dt = tid & 63;
        const float* src = x + ((size_t)(blockBase + rb) * TT + t0 + dt) * II;
        unsigned short* ph = xhi + rb * XP + dt * 8;
        #pragma unroll
        for (int ii = 0; ii < II; ++ii)
            ph[ii] = bf16_rne(src[ii]);
    };

    // ================= prologue: L1(0) =================
    refill_x(0);
    __syncthreads();
    {
        short8 Bxh = *(const short8*)(xhi + b * XP);
        floatx4 a1 = {bias1[0], bias1[1], bias1[2], bias1[3]};
        a1 = MFMA(Axwh, Bxh, a1);
        const float h = cell_update(a1, c1);
        h1hi[0 * HSZ + hw_off] = bf16_rne(h);   // parity 0
    }
    __syncthreads();

    // ================= merged main loop: L2(i) + L1(i+1) =================
    for (int i = 0; i < TT - 1; ++i) {
        if (((i + 1) & 63) == 0) {
            refill_x(i + 1);
            __syncthreads();
        }
        const int wp = i & 1, rp = wp ^ 1;
        const int dt = (i + 1) & 63;

        short8 H1h0 = *(const short8*)(h1hi + wp * HSZ + ro);
        short8 H1h1 = *(const short8*)(h1hi + wp * HSZ + 512 + ro);
        short8 H2h0 = *(const short8*)(h2hi + rp * HSZ + ro);
        short8 H2h1 = *(const short8*)(h2hi + rp * HSZ + 512 + ro);
        short8 Bxh  = *(const short8*)(xhi + b * XP + dt * 8);

        // ---- L2(i): gates from [h1(i); h2(i-1)], single chain ----
        floatx4 a2 = {bias2[0], bias2[1], bias2[2], bias2[3]};
        a2 = MFMA(A2h[0], H1h0, a2);
        a2 = MFMA(A2h[1], H1h1, a2);
        a2 = MFMA(A2h[2], H2h0, a2);
        a2 = MFMA(A2h[3], H2h1, a2);

        // ---- L1(i+1): gates from [x(i+1); h1(i)], single chain ----
        floatx4 a1 = {bias1[0], bias1[1], bias1[2], bias1[3]};
        a1 = MFMA(Axwh, Bxh, a1);
        a1 = MFMA(A1h[0], H1h0, a1);
        a1 = MFMA(A1h[1], H1h1, a1);

        // ---- cell updates ----
        {
            const float h = cell_update(a2, c2);     // h2(i) -> parity wp
            h2hi[wp * HSZ + hw_off] = bf16_rne(h);
        }
        {
            const float h = cell_update(a1, c1);     // h1(i+1) -> parity rp
            h1hi[rp * HSZ + hw_off] = bf16_rne(h);
        }
        __syncthreads();
    }

    // ================= epilogue: L2(255) =================
    {
        const int wp = 1, rp = 0;
        short8 H1h0 = *(const short8*)(h1hi + wp * HSZ + ro);
        short8 H1h1 = *(const short8*)(h1hi + wp * HSZ + 512 + ro);
        short8 H2h0 = *(const short8*)(h2hi + rp * HSZ + ro);
        short8 H2h1 = *(const short8*)(h2hi + rp * HSZ + 512 + ro);
        floatx4 a2 = {bias2[0], bias2[1], bias2[2], bias2[3]};
        a2 = MFMA(A2h[0], H1h0, a2);
        a2 = MFMA(A2h[1], H1h1, a2);
        a2 = MFMA(A2h[2], H2h0, a2);
        a2 = MFMA(A2h[3], H2h1, a2);
        const float h = cell_update(a2, c2);
        h2f[b * HF + jmine] = h;
    }
    __syncthreads();

    // ================= FC epilogue =================
    if (tid < MT * OO) {
        const int bb = tid / OO, o = tid - bb * OO;
        float acc = bfc[o];
        const float* wr = Wfc + o * HH;
        const float* hr = h2f + bb * HF;
        #pragma unroll
        for (int j = 0; j < HH; ++j) acc += wr[j] * hr[j];
        out[((size_t)blockIdx.x * MT + bb) * OO + o] = acc;
    }
}

extern "C" void kernel_launch(void* const* d_in, const int* in_sizes, int n_in,
                              void* d_out, int out_size, void* d_ws, size_t ws_size,
                              hipStream_t stream) {
    const float* x    = (const float*)d_in[0];
    const float* Wih0 = (const float*)d_in[1];
    const float* Whh0 = (const float*)d_in[2];
    const float* bih0 = (const float*)d_in[3];
    const float* bhh0 = (const float*)d_in[4];
    const float* Wih1 = (const float*)d_in[5];
    const float* Whh1 = (const float*)d_in[6];
    const float* bih1 = (const float*)d_in[7];
    const float* bhh1 = (const float*)d_in[8];
    const float* Wfc  = (const float*)d_in[9];
    const float* bfc  = (const float*)d_in[10];
    float* out = (float*)d_out;

    dim3 grid(4096 / MT), block(NTHR);
    lstm_mfma8<<<grid, block, 0, stream>>>(x, Wih0, Whh0, bih0, bhh0,
                                           Wih1, Whh1, bih1, bhh1,
                                           Wfc, bfc, out);
}

// Round 13
// 259.742 us; speedup vs baseline: 1.6992x; 1.0898x over previous
//
#include <hip/hip_runtime.h>

// StockLSTM R13 = R12 + two register-neutral VALU cuts:
//  1) nonlinearity scales folded into weights/biases at preload:
//     sigmoid rows (i,f,o) pre-scaled by -log2(e), tanh-g rows by +2log2(e)
//     -> sig = rcp(1+exp2(z)) [3 inst], tanhg = fma(-2,rcp(1+exp2(z)),1).
//  2) manual unroll-by-2: t-parity is compile-time -> all h-state LDS
//     accesses are {ro,hw_off} reg + immediate offset (no per-step parity
//     address math); x address = one incremented reg, reset at refill.
// Walls (measured this session): 64-VGPR allocator cap, grid=256 -> 1
// block/CU, full h-mixing -> 1 barrier/step minimum.

#define TT   256
#define II   5
#define HH   64
#define OO   25
#define MT   16
#define NTHR 1024
#define XP   520        // x chunk row stride (ushorts): 64*8 + 8 skew
#define HSZ  1024       // h parity block: 64 k * 16 batch shorts
#define HF   65

typedef __attribute__((ext_vector_type(8))) short  short8;
typedef __attribute__((ext_vector_type(4))) float  floatx4;

#define MFMA(a, b, c) __builtin_amdgcn_mfma_f32_16x16x32_bf16(a, b, c, 0, 0, 0)

__device__ __forceinline__ float frcp(float x) { return __builtin_amdgcn_rcpf(x); }
__device__ __forceinline__ float fexp2(float x) { return __builtin_amdgcn_exp2f(x); }
__device__ __forceinline__ unsigned short bf16_rne(float f) {
    unsigned int u = __builtin_bit_cast(unsigned int, f);
    u += 0x7FFFu + ((u >> 16) & 1u);
    return (unsigned short)(u >> 16);
}
// gates arrive PRE-SCALED: g0,g1,g3 = -log2e*z ; g2 = +2log2e*z
__device__ __forceinline__ float cell_update(const floatx4& g, float& c) {
    const float gi = frcp(1.f + fexp2(g[0]));
    const float gf = frcp(1.f + fexp2(g[1]));
    const float gz = fmaf(-2.f, frcp(1.f + fexp2(g[2])), 1.f);
    const float go = frcp(1.f + fexp2(g[3]));
    c = fmaf(gf, c, gi * gz);
    const float tc = fmaf(-2.f, frcp(1.f + fexp2(c * 2.885390082f)), 1.f);
    return go * tc;
}

__global__ __attribute__((amdgpu_flat_work_group_size(1024, 1024),
                          amdgpu_waves_per_eu(4, 4)))
void lstm_mfma9(const float* __restrict__ x,
                const float* __restrict__ Wih0, const float* __restrict__ Whh0,
                const float* __restrict__ bih0, const float* __restrict__ bhh0,
                const float* __restrict__ Wih1, const float* __restrict__ Whh1,
                const float* __restrict__ bih1, const float* __restrict__ bhh1,
                const float* __restrict__ Wfc,  const float* __restrict__ bfc,
                float* __restrict__ out)
{
    __shared__ __align__(16) unsigned short xhi[MT * XP];     // 16.6 KB
    __shared__ __align__(16) unsigned short h1hi[2 * HSZ];    // 4 KB each
    __shared__ __align__(16) unsigned short h2hi[2 * HSZ];
    __shared__ __align__(16) float          h2f[MT * HF];

    const int tid   = threadIdx.x;
    const int w     = tid >> 6;
    const int lane  = tid & 63;
    const int b     = lane & 15;      // batch col
    const int q     = lane >> 4;      // k-slice / C row-quad
    const int jmine = 4 * w + q;
    const int hw_off = ((jmine >> 3) * 16 + b) * 8 + (jmine & 7);
    const int ro     = lane * 8;      // fragment read offset: lane*16B

    // ---------------- weights (bf16), nonlinearity scale folded in ----------------
    short8 A1h[2];   // Whh0 k-chunks
    short8 A2h[4];   // 0,1: Wih1 (h1 side); 2,3: Whh1 (h2 side)
    short8 Axwh;     // Wih0: k<II valid, rest exact zero
    {
        const int rr = lane & 15;
        const int g  = (rr & 3) * 64 + 4 * w + (rr >> 2);
        const float sc = ((rr & 3) == 2) ? 2.885390082f : -1.442695041f;
        #pragma unroll
        for (int c = 0; c < 2; ++c)
            #pragma unroll
            for (int jj = 0; jj < 8; ++jj)
                A1h[c][jj] = (short)bf16_rne(sc * Whh0[g * HH + c * 32 + q * 8 + jj]);
        #pragma unroll
        for (int c = 0; c < 4; ++c)
            #pragma unroll
            for (int jj = 0; jj < 8; ++jj) {
                const int k = c * 32 + q * 8 + jj;
                float wv = (k < HH) ? Wih1[g * HH + k] : Whh1[g * HH + (k - HH)];
                A2h[c][jj] = (short)bf16_rne(sc * wv);
            }
        #pragma unroll
        for (int jj = 0; jj < 8; ++jj) {
            const int k = q * 8 + jj;
            Axwh[jj] = (k < II) ? (short)bf16_rne(sc * Wih0[g * II + k]) : (short)0;
        }
    }
    float bias1[4], bias2[4];
    #pragma unroll
    for (int r = 0; r < 4; ++r) {
        const int g = r * 64 + jmine;
        const float sc = (r == 2) ? 2.885390082f : -1.442695041f;
        bias1[r] = sc * (bih0[g] + bhh0[g]);
        bias2[r] = sc * (bih1[g] + bhh1[g]);
    }

    // ---------------- zero LDS ----------------
    for (int i = tid; i < MT * XP / 2; i += NTHR)
        ((unsigned int*)xhi)[i] = 0u;
    for (int i = tid; i < HSZ; i += NTHR) {
        ((unsigned int*)h1hi)[i] = 0u;
        ((unsigned int*)h2hi)[i] = 0u;
    }
    float c1 = 0.f, c2 = 0.f;
    __syncthreads();

    const int blockBase = blockIdx.x * MT;

    auto refill_x = [&](int t0) {
        const int rb = tid >> 6, dt = tid & 63;
        const float* src = x + ((size_t)(blockBase + rb) * TT + t0 + dt) * II;
        unsigned short* ph = xhi + rb * XP + dt * 8;
        #pragma unroll
        for (int ii = 0; ii < II; ++ii)
            ph[ii] = bf16_rne(src[ii]);
    };

    // ================= prologue: L1(0) =================
    refill_x(0);
    __syncthreads();
    {
        short8 Bxh = *(const short8*)(xhi + b * XP);       // dt = 0
        floatx4 a1 = {bias1[0], bias1[1], bias1[2], bias1[3]};
        a1 = MFMA(Axwh, Bxh, a1);
        const float h = cell_update(a1, c1);
        h1hi[0 * HSZ + hw_off] = bf16_rne(h);              // parity 0
    }
    __syncthreads();

    // x read pointer: STEP(i) reads dt=(i+1)&63; starts at dt=1.
    const unsigned short* xptr = xhi + b * XP + 8;

    // ================= merged main loop, unrolled by 2 =================
    // STEP(WP,RP): compile-time parity -> all h LDS accesses reg+imm.
#define STEP_BODY(WP, RP)                                                     \
    {                                                                         \
        short8 H1h0 = *(const short8*)(h1hi + (WP) * HSZ + ro);               \
        short8 H1h1 = *(const short8*)(h1hi + (WP) * HSZ + 512 + ro);         \
        short8 H2h0 = *(const short8*)(h2hi + (RP) * HSZ + ro);               \
        short8 H2h1 = *(const short8*)(h2hi + (RP) * HSZ + 512 + ro);         \
        short8 Bxh  = *(const short8*)(xptr);                                 \
        xptr += 8;                                                            \
        floatx4 a2 = {bias2[0], bias2[1], bias2[2], bias2[3]};                \
        a2 = MFMA(A2h[0], H1h0, a2);                                          \
        a2 = MFMA(A2h[1], H1h1, a2);                                          \
        a2 = MFMA(A2h[2], H2h0, a2);                                          \
        a2 = MFMA(A2h[3], H2h1, a2);                                          \
        floatx4 a1 = {bias1[0], bias1[1], bias1[2], bias1[3]};                \
        a1 = MFMA(Axwh, Bxh, a1);                                             \
        a1 = MFMA(A1h[0], H1h0, a1);                                          \
        a1 = MFMA(A1h[1], H1h1, a1);                                          \
        {                                                                     \
            const float h = cell_update(a2, c2);                              \
            h2hi[(WP) * HSZ + hw_off] = bf16_rne(h);                          \
        }                                                                     \
        {                                                                     \
            const float h = cell_update(a1, c1);                              \
            h1hi[(RP) * HSZ + hw_off] = bf16_rne(h);                          \
        }                                                                     \
        __syncthreads();                                                      \
    }

    for (int i = 0; i < 254; i += 2) {
        STEP_BODY(0, 1)                      // interval i   (even)
        if (((i + 2) & 63) == 0) {           // refill before interval i+1
            refill_x(i + 2);                 //   when (i+2) % 64 == 0
            xptr = xhi + b * XP;             //   next read is dt = 0
            __syncthreads();
        }
        STEP_BODY(1, 0)                      // interval i+1 (odd)
    }
    STEP_BODY(0, 1)                          // interval 254
#undef STEP_BODY

    // ================= epilogue: L2(255) =================
    {
        short8 H1h0 = *(const short8*)(h1hi + 1 * HSZ + ro);
        short8 H1h1 = *(const short8*)(h1hi + 1 * HSZ + 512 + ro);
        short8 H2h0 = *(const short8*)(h2hi + 0 * HSZ + ro);
        short8 H2h1 = *(const short8*)(h2hi + 0 * HSZ + 512 + ro);
        floatx4 a2 = {bias2[0], bias2[1], bias2[2], bias2[3]};
        a2 = MFMA(A2h[0], H1h0, a2);
        a2 = MFMA(A2h[1], H1h1, a2);
        a2 = MFMA(A2h[2], H2h0, a2);
        a2 = MFMA(A2h[3], H2h1, a2);
        const float h = cell_update(a2, c2);
        h2f[b * HF + jmine] = h;
    }
    __syncthreads();

    // ================= FC epilogue =================
    if (tid < MT * OO) {
        const int bb = tid / OO, o = tid - bb * OO;
        float acc = bfc[o];
        const float* wr = Wfc + o * HH;
        const float* hr = h2f + bb * HF;
        #pragma unroll
        for (int j = 0; j < HH; ++j) acc += wr[j] * hr[j];
        out[((size_t)blockIdx.x * MT + bb) * OO + o] = acc;
    }
}

extern "C" void kernel_launch(void* const* d_in, const int* in_sizes, int n_in,
                              void* d_out, int out_size, void* d_ws, size_t ws_size,
                              hipStream_t stream) {
    const float* x    = (const float*)d_in[0];
    const float* Wih0 = (const float*)d_in[1];
    const float* Whh0 = (const float*)d_in[2];
    const float* bih0 = (const float*)d_in[3];
    const float* bhh0 = (const float*)d_in[4];
    const float* Wih1 = (const float*)d_in[5];
    const float* Whh1 = (const float*)d_in[6];
    const float* bih1 = (const float*)d_in[7];
    const float* bhh1 = (const float*)d_in[8];
    const float* Wfc  = (const float*)d_in[9];
    const float* bfc  = (const float*)d_in[10];
    float* out = (float*)d_out;

    dim3 grid(4096 / MT), block(NTHR);
    lstm_mfma9<<<grid, block, 0, stream>>>(x, Wih0, Whh0, bih0, bhh0,
                                           Wih1, Whh1, bih1, bhh1,
                                           Wfc, bfc, out);
}